// Round 1
// 416.047 us; speedup vs baseline: 1.0063x; 1.0063x over previous
//
#include <hip/hip_runtime.h>

// H=W=1024, T=16, 20 iterations. Intermediates live in two padded+guarded
// zero-bordered buffers. Layout per buffer (floats):
//   [16 slack][guard row][row 0 (border)] ... [row 1025 (border)][guard row]
// PITCH=1040 leaves a 14-float zero gutter per row. All guards/gutters/borders
// are memset-zero once and never written, so ANY clamped sample index reads
// exact 0.0 for out-of-range corners -> zeros padding is exact with NO per-lane
// validity cmp/cndmask.
//
// R6 structure (vs R5):
//  - per-tile coef tables precompacted in GLOBAL memory (setup_tiles), read in
//    ifs_iter via uniform scalar loads -> no LDS, no __syncthreads, no ds_read.
//  - OOB handling via v_med3 clamps into guaranteed-zero guard regions.
//  - transform groups of 8 (16 gathers in flight), remainder group of 4.
constexpr int W = 1024;
constexpr int H = 1024;
constexpr int T = 16;
constexpr int ITERS = 20;
constexpr int PITCH = 1040;              // floats per row
constexpr int PH = H + 2;                // 1026 logical padded rows
constexpr int GROWS = PH + 2;            // + guard row above and below
constexpr int ALLOC = 16 + GROWS * PITCH;  // floats per buffer allocation
constexpr int TILES_X = W / 16;          // 64
constexpr int TILES_Y = H / 16;          // 64
constexpr int NTILES = TILES_X * TILES_Y;

typedef float f2 __attribute__((ext_vector_type(2), aligned(4)));

// coef per transform t: {p, Ax, Bx, Cxb, Ay, By, Cyb, 0}; Cxb/Cyb include the
// +1 pad shift AND +1 clamp bias, so xb = Ax*w + Bx*h + Cxb is the padded x
// coordinate + 1 (>= 0 for any in-range sample).
__global__ void setup_coef(const float* __restrict__ theta,
                           const float* __restrict__ probs,
                           float* __restrict__ coef) {
    int t = threadIdx.x;
    if (t >= T) return;
    float sum = 0.f;
    for (int i = 0; i < T; ++i) sum += probs[i];
    float p = probs[t] / sum;
    const float* th = theta + 6 * t;
    float a = th[0], b = th[1], c = th[2];
    float d = th[3], e = th[4], f = th[5];
    float Cx = a * ((1.0f - (float)W) * 0.5f)
             + b * ((1.0f - (float)H) * 0.5f)
             + (c + 1.0f) * ((float)W * 0.5f) - 0.5f;
    float Cy = d * ((1.0f - (float)W) * 0.5f)
             + e * ((1.0f - (float)H) * 0.5f)
             + (f + 1.0f) * ((float)H * 0.5f) - 0.5f;
    float* o = coef + 8 * t;
    o[0] = p;  o[1] = a;  o[2] = b;  o[3] = Cx + 2.0f;
    o[4] = d;  o[5] = e;  o[6] = Cy + 2.0f; o[7] = 0.f;
}

// One thread per 16x16 tile: conservative bbox hit test (in xb space, so the
// "no contribution" bounds are xb<=1 / xb>=1026), compact the active
// transforms' coef rows into tbl[tile*128 ..], zero-pad count to multiple of 4.
__global__ __launch_bounds__(256) void setup_tiles(const float* __restrict__ coef,
                                                   float* __restrict__ tbl,
                                                   int* __restrict__ tcnt) {
    int tile = blockIdx.x * 256 + threadIdx.x;
    if (tile >= NTILES) return;
    int tx = tile & (TILES_X - 1), ty = tile >> 6;
    float w0 = (float)(tx * 16), w1 = w0 + 15.f;
    float h0 = (float)(ty * 16), h1 = h0 + 15.f;
    float* o = tbl + tile * 128;
    int n = 0;
    for (int t = 0; t < T; ++t) {
        const float* c = coef + t * 8;
        float Ax = c[1], Bx = c[2], Cx = c[3];
        float Ay = c[4], By = c[5], Cy = c[6];
        float xmin = Cx + (Ax >= 0.f ? Ax * w0 : Ax * w1) + (Bx >= 0.f ? Bx * h0 : Bx * h1);
        float xmax = Cx + (Ax >= 0.f ? Ax * w1 : Ax * w0) + (Bx >= 0.f ? Bx * h1 : Bx * h0);
        float ymin = Cy + (Ay >= 0.f ? Ay * w0 : Ay * w1) + (By >= 0.f ? By * h0 : By * h1);
        float ymax = Cy + (Ay >= 0.f ? Ay * w1 : Ay * w0) + (By >= 0.f ? By * h1 : By * h0);
        bool hit = !(xmax <= 1.f || xmin >= (float)(W + 2) ||
                     ymax <= 1.f || ymin >= (float)(H + 2));
        if (hit) {
            for (int j = 0; j < 8; ++j) o[n * 8 + j] = c[j];
            ++n;
        }
    }
    tcnt[tile] = n;
    int np = (n + 3) & ~3;
    for (int s = n; s < np; ++s)          // dummy transforms: all-zero -> p=0
        for (int j = 0; j < 8; ++j) o[s * 8 + j] = 0.f;
}

__global__ __launch_bounds__(256) void copy_in(const float* __restrict__ src,
                                               float* __restrict__ dst) {
    int i = blockIdx.x * 256 + threadIdx.x;   // i in [0, H*W)
    int h = i >> 10, w = i & 1023;
    dst[(h + 1) * PITCH + (w + 1)] = src[i];
}

// K transforms per group: coefs come from uniform scalar loads; OOB handled by
// clamping into guaranteed-zero guard regions (contribution self-annihilates).
template <int K>
__device__ __forceinline__ void ifs_body(const float* __restrict__ tc, int g,
                                         const float* __restrict__ gb,
                                         float wf, float hf, float& acc) {
    float fx[K], fy[K], pp[K];
    int off[K];
#pragma unroll
    for (int k = 0; k < K; ++k) {
        const float* c = tc + (g + k) * 8;          // uniform -> s_load
        float p = c[0], Ax = c[1], Bx = c[2], Cx = c[3];
        float Ay = c[4], By = c[5], Cy = c[6];
        float xb = fmaf(Ax, wf, fmaf(Bx, hf, Cx));  // padded x + 1
        float yb = fmaf(Ay, wf, fmaf(By, hf, Cy));  // padded y + 1
        xb = fminf(fmaxf(xb, 0.f), 1037.f);         // v_med3; cols xi-1,xi <= 1039
        yb = fminf(fmaxf(yb, 0.f), 1026.f);         // rows yi-1,yi <= 1026 (guard)
        float xi = floorf(xb), yi = floorf(yb);
        fx[k] = xb - xi;
        fy[k] = yb - yi;
        off[k] = (int)fmaf(yi, (float)PITCH, xi);   // exact (< 2^24)
        pp[k] = p;                                  // stays in SGPR
    }
    f2 r0[K], r1[K];
#pragma unroll
    for (int k = 0; k < K; ++k) {                   // 2K gathers in flight
        r0[k] = *(const f2*)(gb + off[k]);
        r1[k] = *(const f2*)(gb + off[k] + PITCH);
    }
#pragma unroll
    for (int k = 0; k < K; ++k) {
        float top = fmaf(fx[k], r0[k].y - r0[k].x, r0[k].x);
        float bot = fmaf(fx[k], r1[k].y - r1[k].x, r1[k].x);
        acc = fmaf(pp[k], fmaf(fy[k], bot - top, top), acc);
    }
}

__global__ __launch_bounds__(256) void ifs_iter(const float* __restrict__ in,
                                                float* __restrict__ out,
                                                const float* __restrict__ tbl,
                                                const int* __restrict__ tcnt,
                                                const float* __restrict__ base,
                                                int dstPitch, int dstOff,
                                                int add_base) {
    int tile = blockIdx.y * TILES_X + blockIdx.x;
    const float* tc = tbl + tile * 128;             // uniform
    int np = (tcnt[tile] + 3) & ~3;                 // uniform trip count

    // 8x8-per-wave mapping; 4 waves tile a 16x16 pixel block.
    int lid = threadIdx.x;
    int lane = lid & 63, wv = lid >> 6;
    int w = (blockIdx.x << 4) + ((wv & 1) << 3) + (lane & 7);
    int h = (blockIdx.y << 4) + ((wv >> 1) << 3) + (lane >> 3);
    float wf = (float)w, hf = (float)h;
    // gather base: element (row yi-1, col xi-1) with off = yi*PITCH+xi
    const float* gb = in - (PITCH + 1);

    float acc = 0.f;
    int g = 0;
    for (; g + 8 <= np; g += 8) ifs_body<8>(tc, g, gb, wf, hf, acc);
    if (g < np)                 ifs_body<4>(tc, g, gb, wf, hf, acc);

    if (add_base) acc += base[0];
    out[h * dstPitch + w + dstOff] = acc;
}

extern "C" void kernel_launch(void* const* d_in, const int* in_sizes, int n_in,
                              void* d_out, int out_size, void* d_ws, size_t ws_size,
                              hipStream_t stream) {
    const float* canvas0 = (const float*)d_in[0];
    const float* theta   = (const float*)d_in[1];
    const float* probs   = (const float*)d_in[2];
    const float* base    = (const float*)d_in[3];

    float* raw  = (float*)d_ws;
    float* bufA = raw + 16 + PITCH;                 // logical padded base
    float* bufB = raw + ALLOC + 16 + PITCH;
    float* coef = raw + 2 * ALLOC;
    float* tbl  = coef + T * 8;
    int*   tcnt = (int*)(tbl + NTILES * 128);

    // zero both buffer allocations: borders, gutters, guard rows, slack
    hipMemsetAsync(raw, 0, (size_t)2 * ALLOC * sizeof(float), stream);

    setup_coef<<<1, 64, 0, stream>>>(theta, probs, coef);
    setup_tiles<<<(NTILES + 255) / 256, 256, 0, stream>>>(coef, tbl, tcnt);
    copy_in<<<(H * W) / 256, 256, 0, stream>>>(canvas0, bufA);

    dim3 block(256);
    dim3 grid(TILES_X, TILES_Y);

    const float* cur = bufA;
    for (int i = 0; i < ITERS; ++i) {
        bool last = (i == ITERS - 1);
        float* dst = last ? (float*)d_out : ((i & 1) ? bufA : bufB);
        int dstPitch = last ? W : PITCH;
        int dstOff   = last ? 0 : (PITCH + 1);
        ifs_iter<<<grid, block, 0, stream>>>(cur, dst, tbl, tcnt, base,
                                             dstPitch, dstOff, last ? 1 : 0);
        cur = dst;
    }
}